// Round 16
// baseline (204.160 us; speedup 1.0000x reference)
//
#include <hip/hip_runtime.h>
#include <hip/hip_bf16.h>
#include <math.h>

typedef short bf16x8 __attribute__((ext_vector_type(8)));
typedef float f32x4 __attribute__((ext_vector_type(4)));
typedef float f32x16 __attribute__((ext_vector_type(16)));
typedef __hip_bfloat16 bf16;
typedef unsigned int uint;

static constexpr int Bn = 4, Nn = 2048, Cn = 1024, Hn = 16, Dn = 64;
static constexpr float kEps = 1e-6f;
static constexpr float kQScale = 0.125f * 1.44269504088896340f;  // D^-0.5 * log2(e)

// async global->LDS 16B per lane (wave-uniform dest base + lane*16)
#define GLOAD_LDS16(gp, lp)                                                        \
  __builtin_amdgcn_global_load_lds(                                                \
      (const __attribute__((address_space(1))) unsigned int*)(gp),                 \
      (__attribute__((address_space(3))) unsigned int*)(lp), 16, 0, 0)

// exp2 via intrinsic (NOT inline asm): r10's inline-asm v_exp_f32 read MFMA
// destination registers directly and silently corrupted outputs. The builtin
// is hazard-modeled. r12's ds_read_b64_tr_b16 port also failed (layout
// mis-derived) — flash keeps the r11 LDS access pattern.
__device__ __forceinline__ float exp2_fast(float x) {
#if __has_builtin(__builtin_amdgcn_exp2f)
  return __builtin_amdgcn_exp2f(x);
#else
  return exp2f(x);
#endif
}

// ---------------- f32 -> bf16 convert (4 elems/thread) ----------------
__global__ __launch_bounds__(256) void cvt_kernel(const float* __restrict__ in,
                                                  bf16* __restrict__ out, int n4) {
  int i = blockIdx.x * 256 + threadIdx.x;
  if (i >= n4) return;
  const float4 v = reinterpret_cast<const float4*>(in)[i];
  bf16 t[4];
  t[0] = __float2bfloat16(v.x); t[1] = __float2bfloat16(v.y);
  t[2] = __float2bfloat16(v.z); t[3] = __float2bfloat16(v.w);
  reinterpret_cast<uint2*>(out)[i] = *reinterpret_cast<const uint2*>(t);
}

// ---------------- bf16 GEMM v3 (r15, verified): dbuf + both-sides swizzle ---
template <int EPI>
__global__ __launch_bounds__(256) void gemm_bt(
    const bf16* __restrict__ A, const bf16* __restrict__ Bw,
    float* __restrict__ Cf, bf16* __restrict__ q_raw, bf16* __restrict__ k_raw,
    bf16* __restrict__ v_buf, const float* __restrict__ cosb,
    const float* __restrict__ sinb, const float* __restrict__ nqw,
    const float* __restrict__ nkw, int nxt, int nyt, int N, int K) {
  __shared__ __align__(16) bf16 As[2][128 * 64];
  __shared__ __align__(16) bf16 Bs[2][128 * 64];
  const int tid = threadIdx.x;
  const int lane = tid & 63, w = tid >> 6;
  const int wr = w >> 1, wc = w & 1;
  const int l15 = lane & 15, l4 = lane >> 4;
  const int bid = blockIdx.x;
  const int xcd = bid & 7;
  const int kk2 = bid >> 3;
  const int nslab = nxt >> 3;
  const int mtile = kk2 / nslab;
  const int ntile = xcd * nslab + (kk2 % nslab);
  const int m0 = mtile * 128, n0 = ntile * 128;
  f32x4 acc[4][4] = {};

  const int sr = tid >> 3, sc = (tid & 7) * 8;
  const int srcE = (((sc * 2) ^ ((sr & 7) << 4)) >> 1);  // pre-swizzled src col
  const bf16* const Ap = A + (size_t)(m0 + sr) * K + srcE;
  const bf16* const Bp = Bw + (size_t)(n0 + sr) * K + srcE;

#pragma unroll
  for (int c = 0; c < 4; ++c) {
    GLOAD_LDS16(Ap + (size_t)(c * 32) * K, (char*)As[0] + tid * 16 + c * 4096);
    GLOAD_LDS16(Bp + (size_t)(c * 32) * K, (char*)Bs[0] + tid * 16 + c * 4096);
  }
  __syncthreads();

  const int swzg = (l15 & 7) << 4;  // read-side XOR (row&7 == l15&7)
  int cur = 0;
  for (int k0 = 0; k0 < K; k0 += 64) {
    if (k0 + 64 < K) {
#pragma unroll
      for (int c = 0; c < 4; ++c) {
        GLOAD_LDS16(Ap + (size_t)(c * 32) * K + k0 + 64,
                    (char*)As[cur ^ 1] + tid * 16 + c * 4096);
        GLOAD_LDS16(Bp + (size_t)(c * 32) * K + k0 + 64,
                    (char*)Bs[cur ^ 1] + tid * 16 + c * 4096);
      }
    }
    const char* Ac = (const char*)As[cur];
    const char* Bc = (const char*)Bs[cur];
#pragma unroll
    for (int kc = 0; kc < 2; ++kc) {
      bf16x8 af[4], bfr[4];
#pragma unroll
      for (int mi = 0; mi < 4; ++mi)
        af[mi] = *reinterpret_cast<const bf16x8*>(
            Ac + (wr * 64 + mi * 16 + l15) * 128 + ((kc * 64 + l4 * 16) ^ swzg));
#pragma unroll
      for (int ni = 0; ni < 4; ++ni)
        bfr[ni] = *reinterpret_cast<const bf16x8*>(
            Bc + (wc * 64 + ni * 16 + l15) * 128 + ((kc * 64 + l4 * 16) ^ swzg));
#pragma unroll
      for (int mi = 0; mi < 4; ++mi)
#pragma unroll
        for (int ni = 0; ni < 4; ++ni)
          acc[mi][ni] =
              __builtin_amdgcn_mfma_f32_16x16x32_bf16(af[mi], bfr[ni], acc[mi][ni], 0, 0, 0);
    }
    __syncthreads();
    cur ^= 1;
  }

  if (EPI == 1) {
#pragma unroll
    for (int mi = 0; mi < 4; ++mi)
#pragma unroll
      for (int ni = 0; ni < 4; ++ni)
#pragma unroll
        for (int r = 0; r < 4; ++r) {
          const int row = m0 + wr * 64 + mi * 16 + l4 * 4 + r;
          const int col = n0 + wc * 64 + ni * 16 + l15;
          Cf[(size_t)row * N + col] = acc[mi][ni][r];
        }
    return;
  }

  // ---- EPI 0: fused epilogue ----
  const int colbase = n0 + wc * 64;       // wave-uniform
  const int which = colbase >> 10;        // 0:q 1:k 2:v
  const int hh = (colbase >> 6) & 15;
  if (which == 2) {
#pragma unroll
    for (int mi = 0; mi < 4; ++mi)
#pragma unroll
      for (int r = 0; r < 4; ++r) {
        const int row = m0 + wr * 64 + mi * 16 + l4 * 4 + r;
        const int b = row >> 11, n = row & (Nn - 1);
#pragma unroll
        for (int ni = 0; ni < 4; ++ni) {
          const int d = ni * 16 + l15;
          const size_t idx = (((size_t)b * Hn + hh) * Nn + n) * Dn + d;
          v_buf[idx] = __float2bfloat16(acc[mi][ni][r]);
        }
      }
    return;
  }
  const float* const wgt = which ? nkw : nqw;
  bf16* const dst = which ? k_raw : q_raw;
  float wv4[4];
#pragma unroll
  for (int ni = 0; ni < 4; ++ni) wv4[ni] = wgt[ni * 16 + l15];
#pragma unroll
  for (int mi = 0; mi < 4; ++mi)
#pragma unroll
    for (int r = 0; r < 4; ++r) {
      const int row = m0 + wr * 64 + mi * 16 + l4 * 4 + r;
      const int b = row >> 11, n = row & (Nn - 1);
      float x0 = acc[mi][0][r], x1 = acc[mi][1][r], x2 = acc[mi][2][r], x3 = acc[mi][3][r];
      float ss = x0 * x0 + x1 * x1 + x2 * x2 + x3 * x3;
      ss += __shfl_xor(ss, 1);
      ss += __shfl_xor(ss, 2);
      ss += __shfl_xor(ss, 4);
      ss += __shfl_xor(ss, 8);
      const float rinv = rsqrtf(ss * (1.f / Dn) + kEps);
      float nx[4] = {x0 * rinv * wv4[0], x1 * rinv * wv4[1], x2 * rinv * wv4[2],
                     x3 * rinv * wv4[3]};
#pragma unroll
      for (int ni = 0; ni < 4; ++ni) {
        const int d = ni * 16 + l15;
        const float c = cosb[n * Dn + d], s = sinb[n * Dn + d];
        const float sgn = (ni < 2) ? -1.f : 1.f;
        float val = nx[ni] * c + sgn * nx[ni ^ 2] * s;
        if (which == 0) val *= kQScale;
        const size_t idx = (((size_t)b * Hn + hh) * Nn + n) * Dn + d;
        dst[idx] = __float2bfloat16(val);
      }
    }
}

// ---------------- flash attention v15: 4-buffer, 2 tiles per barrier --------
// r15's counters showed ~65% dependency-stall at 4 waves/SIMD (MFMA 31% +
// VALU 43%, barriers cheap, FETCH L3-served): the 1-tile barrier window left
// the serial S->exp2->cvt->PV chain exposed. Now 4 LDS buffers (32 KB):
// super-iter s stages tiles t+2,t+3, computes t and t+1 back-to-back, ONE
// barrier. Compiler gets two independent dependency trees per region
// (tile-B's ds_reads/S-MFMAs interleave under tile-A's softmax), DMAs get
// ~2 compute phases of cover, barrier count halves. Plain __syncthreads
// correctness: buffer staged at s is read at s+1 (drained by s's barrier),
// rewritten at s+2 (reads fenced by s+1's barrier).
__global__ __launch_bounds__(256, 4) void flash_attn(
    const bf16* __restrict__ Qb, const bf16* __restrict__ Kb,
    const bf16* __restrict__ Vb, bf16* __restrict__ Ob) {
  __shared__ __align__(16) char KsB[4][32 * 128];  // 16 KB
  __shared__ __align__(16) char VtB[4][64 * 64];   // 16 KB
  const int bid = blockIdx.x;
  const int xcd = bid & 7;
  const int kidx = bid >> 3;                 // 0..127
  const int bh = xcd * 8 + (kidx >> 4);      // head slab per XCD (L2 locality)
  const int q0 = (kidx & 15) * 128;
  const int tid = threadIdx.x, lane = tid & 63, w = tid >> 6;
  const int l31 = lane & 31, hi = lane >> 5;
  const bf16* Qp = Qb + (size_t)bh * Nn * Dn;
  const bf16* Kp = Kb + (size_t)bh * Nn * Dn;
  const bf16* Vp = Vb + (size_t)bh * Nn * Dn;

  const int qrow = q0 + w * 32 + l31;
  bf16x8 qf[4];
#pragma unroll
  for (int dm = 0; dm < 4; ++dm)
    qf[dm] = *reinterpret_cast<const bf16x8*>(&Qp[(size_t)qrow * Dn + dm * 16 + hi * 8]);

  f32x16 Ot0 = {}, Ot1 = {}, Lacc = {};

  const int skk = tid >> 3, sd0 = (tid & 7) * 8;
  const int srcKe = (((sd0 * 2) ^ ((skk & 7) << 4)) >> 1);  // pre-swizzled src col

  auto stage_v = [&](char* Vn, const uint4& a) {
    const uint wa[4] = {a.x, a.y, a.z, a.w};
#pragma unroll
    for (int j = 0; j < 8; ++j) {
      const int d = sd0 + j;
      const int xs = (((d >> 1) ^ (d >> 3)) & 3) << 4;
      const unsigned short va = (j & 1) ? (unsigned short)(wa[j >> 1] >> 16)
                                        : (unsigned short)(wa[j >> 1] & 0xffff);
      *reinterpret_cast<unsigned short*>(Vn + d * 64 + ((skk * 2) ^ xs)) = va;
    }
  };

  // prologue: tiles 0,1 staged; V tiles 2,3 preloaded to regs (NT = 64)
  GLOAD_LDS16(Kp + (size_t)skk * Dn + srcKe, KsB[0] + tid * 16);
  GLOAD_LDS16(Kp + (size_t)(32 + skk) * Dn + srcKe, KsB[1] + tid * 16);
  {
    uint4 cv0 = *reinterpret_cast<const uint4*>(&Vp[(size_t)skk * Dn + sd0]);
    uint4 cv1 = *reinterpret_cast<const uint4*>(&Vp[(size_t)(32 + skk) * Dn + sd0]);
    stage_v(VtB[0], cv0);
    stage_v(VtB[1], cv1);
  }
  uint4 nva = *reinterpret_cast<const uint4*>(&Vp[(size_t)(64 + skk) * Dn + sd0]);
  uint4 nvb = *reinterpret_cast<const uint4*>(&Vp[(size_t)(96 + skk) * Dn + sd0]);
  __syncthreads();

  const int swzk_rd = (l31 & 7) << 4;
  const int xs0 = ((((l31) >> 1) ^ ((l31) >> 3)) & 3) << 4;
  const int xs1 = ((((32 + l31) >> 1) ^ ((32 + l31) >> 3)) & 3) << 4;

  for (int t = 0; t < 64; t += 2) {  // tile index (32 rows each), 32 super-iters
    // ---- stage tiles t+2, t+3; preload V regs for t+4, t+5 ----
    if (t + 2 < 64) {
      GLOAD_LDS16(Kp + (size_t)((t + 2) * 32 + skk) * Dn + srcKe,
                  KsB[(t + 2) & 3] + tid * 16);
      GLOAD_LDS16(Kp + (size_t)((t + 3) * 32 + skk) * Dn + srcKe,
                  KsB[(t + 3) & 3] + tid * 16);
      stage_v(VtB[(t + 2) & 3], nva);
      stage_v(VtB[(t + 3) & 3], nvb);
      if (t + 4 < 64) {
        nva = *reinterpret_cast<const uint4*>(&Vp[(size_t)((t + 4) * 32 + skk) * Dn + sd0]);
        nvb = *reinterpret_cast<const uint4*>(&Vp[(size_t)((t + 5) * 32 + skk) * Dn + sd0]);
      }
    }

    // ---- compute tiles t and t+1 (independent dep-trees; compiler overlaps)
#pragma unroll
    for (int u = 0; u < 2; ++u) {
      const char* Kc = KsB[(t + u) & 3];
      const char* Vc = VtB[(t + u) & 3];

      f32x16 S0 = {};
      __builtin_amdgcn_s_setprio(1);
#pragma unroll
      for (int dm = 0; dm < 4; ++dm) {
        bf16x8 kf = *reinterpret_cast<const bf16x8*>(
            Kc + l31 * 128 + ((dm * 32 + hi * 16) ^ swzk_rd));
        S0 = __builtin_amdgcn_mfma_f32_32x32x16_bf16(kf, qf[dm], S0, 0, 0, 0);
      }
      __builtin_amdgcn_s_setprio(0);

#pragma unroll
      for (int i = 0; i < 16; ++i) S0[i] = exp2_fast(S0[i]);
#pragma unroll
      for (int i = 0; i < 16; ++i) Lacc[i] += S0[i];
      uint wv[8];
#pragma unroll
      for (int c = 0; c < 2; ++c) {
        uint w0, w1, w2, w3;
        asm("v_cvt_pk_bf16_f32 %0, %1, %2" : "=v"(w0) : "v"(S0[8 * c + 0]), "v"(S0[8 * c + 1]));
        asm("v_cvt_pk_bf16_f32 %0, %1, %2" : "=v"(w1) : "v"(S0[8 * c + 2]), "v"(S0[8 * c + 3]));
        asm("v_cvt_pk_bf16_f32 %0, %1, %2" : "=v"(w2) : "v"(S0[8 * c + 4]), "v"(S0[8 * c + 5]));
        asm("v_cvt_pk_bf16_f32 %0, %1, %2" : "=v"(w3) : "v"(S0[8 * c + 6]), "v"(S0[8 * c + 7]));
        asm("v_permlane32_swap_b32 %0, %1" : "+v"(w0), "+v"(w2));
        asm("v_permlane32_swap_b32 %0, %1" : "+v"(w1), "+v"(w3));
        wv[c * 4 + 0] = w0; wv[c * 4 + 1] = w1;
        wv[c * 4 + 2] = w2; wv[c * 4 + 3] = w3;
      }

      __builtin_amdgcn_s_setprio(1);
#pragma unroll
      for (int s = 0; s < 2; ++s) {
        const uint4 uu = {wv[s * 4 + 0], wv[s * 4 + 1], wv[s * 4 + 2], wv[s * 4 + 3]};
        const bf16x8 pa = __builtin_bit_cast(bf16x8, uu);
        bf16x8 vf0 = *reinterpret_cast<const bf16x8*>(
            Vc + l31 * 64 + ((s * 32 + hi * 16) ^ xs0));
        Ot0 = __builtin_amdgcn_mfma_f32_32x32x16_bf16(vf0, pa, Ot0, 0, 0, 0);
        bf16x8 vf1 = *reinterpret_cast<const bf16x8*>(
            Vc + (32 + l31) * 64 + ((s * 32 + hi * 16) ^ xs1));
        Ot1 = __builtin_amdgcn_mfma_f32_32x32x16_bf16(vf1, pa, Ot1, 0, 0, 0);
      }
      __builtin_amdgcn_s_setprio(0);
    }

    __syncthreads();  // drains DMAs/ds_writes for t+2,t+3; fences buffer reuse
  }

  // ---- final l reduce ----
  float l_r = ((Lacc[0] + Lacc[1]) + (Lacc[2] + Lacc[3])) +
              ((Lacc[4] + Lacc[5]) + (Lacc[6] + Lacc[7])) +
              ((Lacc[8] + Lacc[9]) + (Lacc[10] + Lacc[11])) +
              ((Lacc[12] + Lacc[13]) + (Lacc[14] + Lacc[15]));
  l_r += __shfl_xor(l_r, 32);

  // ---- epilogue ----
  const float inv = 1.f / l_r;
  const int b = bh >> 4, h = bh & 15;
#pragma unroll
  for (int dc = 0; dc < 2; ++dc)
#pragma unroll
    for (int a2 = 0; a2 < 4; ++a2) {
      const f32x16& O = dc ? Ot1 : Ot0;
      unsigned short u0 = __bfloat16_as_ushort(__float2bfloat16(O[a2 * 4 + 0] * inv));
      unsigned short u1 = __bfloat16_as_ushort(__float2bfloat16(O[a2 * 4 + 1] * inv));
      unsigned short u2 = __bfloat16_as_ushort(__float2bfloat16(O[a2 * 4 + 2] * inv));
      unsigned short u3 = __bfloat16_as_ushort(__float2bfloat16(O[a2 * 4 + 3] * inv));
      uint2 pk;
      pk.x = (uint)u0 | ((uint)u1 << 16);
      pk.y = (uint)u2 | ((uint)u3 << 16);
      const int col = h * 64 + dc * 32 + a2 * 8 + hi * 4;
      *reinterpret_cast<uint2*>(&Ob[((size_t)(b * Nn + qrow)) * Cn + col]) = pk;
    }
}

extern "C" void kernel_launch(void* const* d_in, const int* in_sizes, int n_in,
                              void* d_out, int out_size, void* d_ws, size_t ws_size,
                              hipStream_t stream) {
  const float* hs   = (const float*)d_in[0];
  const float* cosb = (const float*)d_in[1];
  const float* sinb = (const float*)d_in[2];
  const float* qkvw = (const float*)d_in[3];
  const float* outw = (const float*)d_in[4];
  const float* nqw  = (const float*)d_in[5];
  const float* nkw  = (const float*)d_in[6];
  float* out = (float*)d_out;

  char* ws = (char*)d_ws;
  size_t off = 0;
  bf16* hs_b   = (bf16*)(ws + off); off += (size_t)Bn * Nn * Cn * 2;
  bf16* qkvw_b = (bf16*)(ws + off); off += (size_t)3 * Cn * Cn * 2;
  bf16* outw_b = (bf16*)(ws + off); off += (size_t)Cn * Cn * 2;
  bf16* q_raw  = (bf16*)(ws + off); off += (size_t)Bn * Hn * Nn * Dn * 2;
  bf16* k_raw  = (bf16*)(ws + off); off += (size_t)Bn * Hn * Nn * Dn * 2;
  bf16* v_buf  = (bf16*)(ws + off); off += (size_t)Bn * Hn * Nn * Dn * 2;
  bf16* attn   = (bf16*)(ws + off); off += (size_t)Bn * Nn * Cn * 2;

  cvt_kernel<<<(Bn * Nn * Cn / 4 + 255) / 256, 256, 0, stream>>>(hs, hs_b, Bn * Nn * Cn / 4);
  cvt_kernel<<<(3 * Cn * Cn / 4 + 255) / 256, 256, 0, stream>>>(qkvw, qkvw_b, 3 * Cn * Cn / 4);
  cvt_kernel<<<(Cn * Cn / 4 + 255) / 256, 256, 0, stream>>>(outw, outw_b, Cn * Cn / 4);

  // QKV projection + fused RMSNorm/RoPE epilogue. grid 1D: 24 n-tiles x 64 m.
  gemm_bt<0><<<24 * 64, 256, 0, stream>>>(
      hs_b, qkvw_b, nullptr, q_raw, k_raw, v_buf, cosb, sinb, nqw, nkw,
      24, 64, 3 * Cn, Cn);

  flash_attn<<<Nn / 128 * Bn * Hn, 256, 0, stream>>>(q_raw, k_raw, v_buf, attn);

  // out projection. grid 1D: 8 n-tiles x 64 m.
  gemm_bt<1><<<8 * 64, 256, 0, stream>>>(
      attn, outw_b, out, nullptr, nullptr, nullptr, nullptr, nullptr, nullptr, nullptr,
      8, 64, Cn, Cn);
}

// Round 17
// 198.678 us; speedup vs baseline: 1.0276x; 1.0276x over previous
//
#include <hip/hip_runtime.h>
#include <hip/hip_bf16.h>
#include <math.h>

typedef short bf16x8 __attribute__((ext_vector_type(8)));
typedef float f32x4 __attribute__((ext_vector_type(4)));
typedef float f32x16 __attribute__((ext_vector_type(16)));
typedef __hip_bfloat16 bf16;
typedef unsigned int uint;

static constexpr int Bn = 4, Nn = 2048, Cn = 1024, Hn = 16, Dn = 64;
static constexpr float kEps = 1e-6f;
static constexpr float kQScale = 0.125f * 1.44269504088896340f;  // D^-0.5 * log2(e)

// async global->LDS 16B per lane (wave-uniform dest base + lane*16)
#define GLOAD_LDS16(gp, lp)                                                        \
  __builtin_amdgcn_global_load_lds(                                                \
      (const __attribute__((address_space(1))) unsigned int*)(gp),                 \
      (__attribute__((address_space(3))) unsigned int*)(lp), 16, 0, 0)

// exp2 via intrinsic (NOT inline asm): r10's inline-asm v_exp_f32 read MFMA
// destination registers directly and silently corrupted outputs. The builtin
// is hazard-modeled. r12's tr_b16 port failed (layout mis-derived); r16's
// 4-buffer/2-tile widening spilled (+22.5MB WRITE) and lost 3µs — flash is
// locked to the r15 structure.
__device__ __forceinline__ float exp2_fast(float x) {
#if __has_builtin(__builtin_amdgcn_exp2f)
  return __builtin_amdgcn_exp2f(x);
#else
  return exp2f(x);
#endif
}

// ---------------- fused f32 -> bf16 convert over 3 segments ----------------
// One dispatch replaces three tiny launches (hs, qkv_w, out_w).
__global__ __launch_bounds__(256) void cvt3_kernel(
    const float* __restrict__ in0, bf16* __restrict__ out0, int n0,   // hs
    const float* __restrict__ in1, bf16* __restrict__ out1, int n1,   // qkv_w
    const float* __restrict__ in2, bf16* __restrict__ out2, int n2) { // out_w
  const int total = n0 + n1 + n2;
  for (int i = blockIdx.x * 256 + threadIdx.x; i < total; i += gridDim.x * 256) {
    const float* src; bf16* dst; int j = i;
    if (j < n0) { src = in0; dst = out0; }
    else if ((j -= n0) < n1) { src = in1; dst = out1; }
    else { j -= n1; src = in2; dst = out2; }
    const float4 v = reinterpret_cast<const float4*>(src)[j];
    bf16 t[4];
    t[0] = __float2bfloat16(v.x); t[1] = __float2bfloat16(v.y);
    t[2] = __float2bfloat16(v.z); t[3] = __float2bfloat16(v.w);
    reinterpret_cast<uint2*>(dst)[j] = *reinterpret_cast<const uint2*>(t);
  }
}

// ---------------- bf16 GEMM v3 (r15, verified): dbuf + both-sides swizzle ---
template <int EPI>
__global__ __launch_bounds__(256) void gemm_bt(
    const bf16* __restrict__ A, const bf16* __restrict__ Bw,
    float* __restrict__ Cf, bf16* __restrict__ q_raw, bf16* __restrict__ k_raw,
    bf16* __restrict__ v_buf, const float* __restrict__ cosb,
    const float* __restrict__ sinb, const float* __restrict__ nqw,
    const float* __restrict__ nkw, int nxt, int nyt, int N, int K) {
  __shared__ __align__(16) bf16 As[2][128 * 64];
  __shared__ __align__(16) bf16 Bs[2][128 * 64];
  const int tid = threadIdx.x;
  const int lane = tid & 63, w = tid >> 6;
  const int wr = w >> 1, wc = w & 1;
  const int l15 = lane & 15, l4 = lane >> 4;
  const int bid = blockIdx.x;
  const int xcd = bid & 7;
  const int kk2 = bid >> 3;
  const int nslab = nxt >> 3;
  const int mtile = kk2 / nslab;
  const int ntile = xcd * nslab + (kk2 % nslab);
  const int m0 = mtile * 128, n0 = ntile * 128;
  f32x4 acc[4][4] = {};

  const int sr = tid >> 3, sc = (tid & 7) * 8;
  const int srcE = (((sc * 2) ^ ((sr & 7) << 4)) >> 1);  // pre-swizzled src col
  const bf16* const Ap = A + (size_t)(m0 + sr) * K + srcE;
  const bf16* const Bp = Bw + (size_t)(n0 + sr) * K + srcE;

#pragma unroll
  for (int c = 0; c < 4; ++c) {
    GLOAD_LDS16(Ap + (size_t)(c * 32) * K, (char*)As[0] + tid * 16 + c * 4096);
    GLOAD_LDS16(Bp + (size_t)(c * 32) * K, (char*)Bs[0] + tid * 16 + c * 4096);
  }
  __syncthreads();

  const int swzg = (l15 & 7) << 4;  // read-side XOR (row&7 == l15&7)
  int cur = 0;
  for (int k0 = 0; k0 < K; k0 += 64) {
    if (k0 + 64 < K) {
#pragma unroll
      for (int c = 0; c < 4; ++c) {
        GLOAD_LDS16(Ap + (size_t)(c * 32) * K + k0 + 64,
                    (char*)As[cur ^ 1] + tid * 16 + c * 4096);
        GLOAD_LDS16(Bp + (size_t)(c * 32) * K + k0 + 64,
                    (char*)Bs[cur ^ 1] + tid * 16 + c * 4096);
      }
    }
    const char* Ac = (const char*)As[cur];
    const char* Bc = (const char*)Bs[cur];
#pragma unroll
    for (int kc = 0; kc < 2; ++kc) {
      bf16x8 af[4], bfr[4];
#pragma unroll
      for (int mi = 0; mi < 4; ++mi)
        af[mi] = *reinterpret_cast<const bf16x8*>(
            Ac + (wr * 64 + mi * 16 + l15) * 128 + ((kc * 64 + l4 * 16) ^ swzg));
#pragma unroll
      for (int ni = 0; ni < 4; ++ni)
        bfr[ni] = *reinterpret_cast<const bf16x8*>(
            Bc + (wc * 64 + ni * 16 + l15) * 128 + ((kc * 64 + l4 * 16) ^ swzg));
#pragma unroll
      for (int mi = 0; mi < 4; ++mi)
#pragma unroll
        for (int ni = 0; ni < 4; ++ni)
          acc[mi][ni] =
              __builtin_amdgcn_mfma_f32_16x16x32_bf16(af[mi], bfr[ni], acc[mi][ni], 0, 0, 0);
    }
    __syncthreads();
    cur ^= 1;
  }

  if (EPI == 1) {
#pragma unroll
    for (int mi = 0; mi < 4; ++mi)
#pragma unroll
      for (int ni = 0; ni < 4; ++ni)
#pragma unroll
        for (int r = 0; r < 4; ++r) {
          const int row = m0 + wr * 64 + mi * 16 + l4 * 4 + r;
          const int col = n0 + wc * 64 + ni * 16 + l15;
          Cf[(size_t)row * N + col] = acc[mi][ni][r];
        }
    return;
  }

  // ---- EPI 0: fused epilogue ----
  const int colbase = n0 + wc * 64;       // wave-uniform
  const int which = colbase >> 10;        // 0:q 1:k 2:v
  const int hh = (colbase >> 6) & 15;
  if (which == 2) {
#pragma unroll
    for (int mi = 0; mi < 4; ++mi)
#pragma unroll
      for (int r = 0; r < 4; ++r) {
        const int row = m0 + wr * 64 + mi * 16 + l4 * 4 + r;
        const int b = row >> 11, n = row & (Nn - 1);
#pragma unroll
        for (int ni = 0; ni < 4; ++ni) {
          const int d = ni * 16 + l15;
          const size_t idx = (((size_t)b * Hn + hh) * Nn + n) * Dn + d;
          v_buf[idx] = __float2bfloat16(acc[mi][ni][r]);
        }
      }
    return;
  }
  const float* const wgt = which ? nkw : nqw;
  bf16* const dst = which ? k_raw : q_raw;
  float wv4[4];
#pragma unroll
  for (int ni = 0; ni < 4; ++ni) wv4[ni] = wgt[ni * 16 + l15];
#pragma unroll
  for (int mi = 0; mi < 4; ++mi)
#pragma unroll
    for (int r = 0; r < 4; ++r) {
      const int row = m0 + wr * 64 + mi * 16 + l4 * 4 + r;
      const int b = row >> 11, n = row & (Nn - 1);
      float x0 = acc[mi][0][r], x1 = acc[mi][1][r], x2 = acc[mi][2][r], x3 = acc[mi][3][r];
      float ss = x0 * x0 + x1 * x1 + x2 * x2 + x3 * x3;
      ss += __shfl_xor(ss, 1);
      ss += __shfl_xor(ss, 2);
      ss += __shfl_xor(ss, 4);
      ss += __shfl_xor(ss, 8);
      const float rinv = rsqrtf(ss * (1.f / Dn) + kEps);
      float nx[4] = {x0 * rinv * wv4[0], x1 * rinv * wv4[1], x2 * rinv * wv4[2],
                     x3 * rinv * wv4[3]};
#pragma unroll
      for (int ni = 0; ni < 4; ++ni) {
        const int d = ni * 16 + l15;
        const float c = cosb[n * Dn + d], s = sinb[n * Dn + d];
        const float sgn = (ni < 2) ? -1.f : 1.f;
        float val = nx[ni] * c + sgn * nx[ni ^ 2] * s;
        if (which == 0) val *= kQScale;
        const size_t idx = (((size_t)b * Hn + hh) * Nn + n) * Dn + d;
        dst[idx] = __float2bfloat16(val);
      }
    }
}

// ---------------- flash attention (r15, verified): bounded-score softmax ----
// 2-buffer, KVBLK=32, vector l-acc, exp2-domain no-max softmax.
__global__ __launch_bounds__(256, 4) void flash_attn(
    const bf16* __restrict__ Qb, const bf16* __restrict__ Kb,
    const bf16* __restrict__ Vb, bf16* __restrict__ Ob) {
  __shared__ __align__(16) char KsB[2][32 * 128];  // 8 KB
  __shared__ __align__(16) char VtB[2][64 * 64];   // 8 KB
  const int bid = blockIdx.x;
  const int xcd = bid & 7;
  const int kidx = bid >> 3;                 // 0..127
  const int bh = xcd * 8 + (kidx >> 4);      // head slab per XCD (L2 locality)
  const int q0 = (kidx & 15) * 128;
  const int tid = threadIdx.x, lane = tid & 63, w = tid >> 6;
  const int l31 = lane & 31, hi = lane >> 5;
  const bf16* Qp = Qb + (size_t)bh * Nn * Dn;
  const bf16* Kp = Kb + (size_t)bh * Nn * Dn;
  const bf16* Vp = Vb + (size_t)bh * Nn * Dn;

  const int qrow = q0 + w * 32 + l31;
  bf16x8 qf[4];
#pragma unroll
  for (int dm = 0; dm < 4; ++dm)
    qf[dm] = *reinterpret_cast<const bf16x8*>(&Qp[(size_t)qrow * Dn + dm * 16 + hi * 8]);

  f32x16 Ot0 = {}, Ot1 = {}, Lacc = {};

  const int skk = tid >> 3, sd0 = (tid & 7) * 8;
  const int srcKe = (((sd0 * 2) ^ ((skk & 7) << 4)) >> 1);  // pre-swizzled src col

  auto stage_v = [&](char* Vn, const uint4& a) {
    const uint wa[4] = {a.x, a.y, a.z, a.w};
#pragma unroll
    for (int j = 0; j < 8; ++j) {
      const int d = sd0 + j;
      const int xs = (((d >> 1) ^ (d >> 3)) & 3) << 4;
      const unsigned short va = (j & 1) ? (unsigned short)(wa[j >> 1] >> 16)
                                        : (unsigned short)(wa[j >> 1] & 0xffff);
      *reinterpret_cast<unsigned short*>(Vn + d * 64 + ((skk * 2) ^ xs)) = va;
    }
  };

  GLOAD_LDS16(Kp + (size_t)skk * Dn + srcKe, KsB[0] + tid * 16);
  {
    uint4 cv = *reinterpret_cast<const uint4*>(&Vp[(size_t)skk * Dn + sd0]);
    stage_v(VtB[0], cv);
  }
  uint4 nv = *reinterpret_cast<const uint4*>(&Vp[(size_t)(32 + skk) * Dn + sd0]);
  __syncthreads();

  const int swzk_rd = (l31 & 7) << 4;
  const int xs0 = ((((l31) >> 1) ^ ((l31) >> 3)) & 3) << 4;
  const int xs1 = ((((32 + l31) >> 1) ^ ((32 + l31) >> 3)) & 3) << 4;
  int cur = 0;
  for (int k0 = 0; k0 < Nn; k0 += 32) {
    const char* Kc = KsB[cur];
    const char* Vc = VtB[cur];

    if (k0 + 32 < Nn) {
      GLOAD_LDS16(Kp + (size_t)(k0 + 32 + skk) * Dn + srcKe, KsB[cur ^ 1] + tid * 16);
      stage_v(VtB[cur ^ 1], nv);
      if (k0 + 64 < Nn)
        nv = *reinterpret_cast<const uint4*>(&Vp[(size_t)(k0 + 64 + skk) * Dn + sd0]);
    }

    // ---- S^T = K · Q^T : 4 MFMAs ----
    f32x16 S0 = {};
    __builtin_amdgcn_s_setprio(1);
#pragma unroll
    for (int dm = 0; dm < 4; ++dm) {
      bf16x8 kf = *reinterpret_cast<const bf16x8*>(
          Kc + l31 * 128 + ((dm * 32 + hi * 16) ^ swzk_rd));
      S0 = __builtin_amdgcn_mfma_f32_32x32x16_bf16(kf, qf[dm], S0, 0, 0, 0);
    }
    __builtin_amdgcn_s_setprio(0);

    // ---- softmax numerators: p = exp2(raw score); vector l accumulation ----
#pragma unroll
    for (int i = 0; i < 16; ++i) S0[i] = exp2_fast(S0[i]);
#pragma unroll
    for (int i = 0; i < 16; ++i) Lacc[i] += S0[i];
    uint wv[8];
#pragma unroll
    for (int c = 0; c < 2; ++c) {
      uint w0, w1, w2, w3;
      asm("v_cvt_pk_bf16_f32 %0, %1, %2" : "=v"(w0) : "v"(S0[8 * c + 0]), "v"(S0[8 * c + 1]));
      asm("v_cvt_pk_bf16_f32 %0, %1, %2" : "=v"(w1) : "v"(S0[8 * c + 2]), "v"(S0[8 * c + 3]));
      asm("v_cvt_pk_bf16_f32 %0, %1, %2" : "=v"(w2) : "v"(S0[8 * c + 4]), "v"(S0[8 * c + 5]));
      asm("v_cvt_pk_bf16_f32 %0, %1, %2" : "=v"(w3) : "v"(S0[8 * c + 6]), "v"(S0[8 * c + 7]));
      asm("v_permlane32_swap_b32 %0, %1" : "+v"(w0), "+v"(w2));
      asm("v_permlane32_swap_b32 %0, %1" : "+v"(w1), "+v"(w3));
      wv[c * 4 + 0] = w0; wv[c * 4 + 1] = w1;
      wv[c * 4 + 2] = w2; wv[c * 4 + 3] = w3;
    }

    // ---- O^T += V^T · P^T : 4 MFMAs ----
    __builtin_amdgcn_s_setprio(1);
#pragma unroll
    for (int s = 0; s < 2; ++s) {
      const uint4 uu = {wv[s * 4 + 0], wv[s * 4 + 1], wv[s * 4 + 2], wv[s * 4 + 3]};
      const bf16x8 pa = __builtin_bit_cast(bf16x8, uu);
      bf16x8 vf0 = *reinterpret_cast<const bf16x8*>(
          Vc + l31 * 64 + ((s * 32 + hi * 16) ^ xs0));
      Ot0 = __builtin_amdgcn_mfma_f32_32x32x16_bf16(vf0, pa, Ot0, 0, 0, 0);
      bf16x8 vf1 = *reinterpret_cast<const bf16x8*>(
          Vc + (32 + l31) * 64 + ((s * 32 + hi * 16) ^ xs1));
      Ot1 = __builtin_amdgcn_mfma_f32_32x32x16_bf16(vf1, pa, Ot1, 0, 0, 0);
    }
    __builtin_amdgcn_s_setprio(0);

    __syncthreads();
    cur ^= 1;
  }

  // ---- final l reduce ----
  float l_r = ((Lacc[0] + Lacc[1]) + (Lacc[2] + Lacc[3])) +
              ((Lacc[4] + Lacc[5]) + (Lacc[6] + Lacc[7])) +
              ((Lacc[8] + Lacc[9]) + (Lacc[10] + Lacc[11])) +
              ((Lacc[12] + Lacc[13]) + (Lacc[14] + Lacc[15]));
  l_r += __shfl_xor(l_r, 32);

  // ---- epilogue ----
  const float inv = 1.f / l_r;
  const int b = bh >> 4, h = bh & 15;
#pragma unroll
  for (int dc = 0; dc < 2; ++dc)
#pragma unroll
    for (int a2 = 0; a2 < 4; ++a2) {
      const f32x16& O = dc ? Ot1 : Ot0;
      unsigned short u0 = __bfloat16_as_ushort(__float2bfloat16(O[a2 * 4 + 0] * inv));
      unsigned short u1 = __bfloat16_as_ushort(__float2bfloat16(O[a2 * 4 + 1] * inv));
      unsigned short u2 = __bfloat16_as_ushort(__float2bfloat16(O[a2 * 4 + 2] * inv));
      unsigned short u3 = __bfloat16_as_ushort(__float2bfloat16(O[a2 * 4 + 3] * inv));
      uint2 pk;
      pk.x = (uint)u0 | ((uint)u1 << 16);
      pk.y = (uint)u2 | ((uint)u3 << 16);
      const int col = h * 64 + dc * 32 + a2 * 8 + hi * 4;
      *reinterpret_cast<uint2*>(&Ob[((size_t)(b * Nn + qrow)) * Cn + col]) = pk;
    }
}

extern "C" void kernel_launch(void* const* d_in, const int* in_sizes, int n_in,
                              void* d_out, int out_size, void* d_ws, size_t ws_size,
                              hipStream_t stream) {
  const float* hs   = (const float*)d_in[0];
  const float* cosb = (const float*)d_in[1];
  const float* sinb = (const float*)d_in[2];
  const float* qkvw = (const float*)d_in[3];
  const float* outw = (const float*)d_in[4];
  const float* nqw  = (const float*)d_in[5];
  const float* nkw  = (const float*)d_in[6];
  float* out = (float*)d_out;

  char* ws = (char*)d_ws;
  size_t off = 0;
  bf16* hs_b   = (bf16*)(ws + off); off += (size_t)Bn * Nn * Cn * 2;
  bf16* qkvw_b = (bf16*)(ws + off); off += (size_t)3 * Cn * Cn * 2;
  bf16* outw_b = (bf16*)(ws + off); off += (size_t)Cn * Cn * 2;
  bf16* q_raw  = (bf16*)(ws + off); off += (size_t)Bn * Hn * Nn * Dn * 2;
  bf16* k_raw  = (bf16*)(ws + off); off += (size_t)Bn * Hn * Nn * Dn * 2;
  bf16* v_buf  = (bf16*)(ws + off); off += (size_t)Bn * Hn * Nn * Dn * 2;
  bf16* attn   = (bf16*)(ws + off); off += (size_t)Bn * Nn * Cn * 2;

  // one fused convert dispatch (hs, qkv_w, out_w), grid-stride
  cvt3_kernel<<<2048, 256, 0, stream>>>(
      hs, hs_b, Bn * Nn * Cn / 4,
      qkvw, qkvw_b, 3 * Cn * Cn / 4,
      outw, outw_b, Cn * Cn / 4);

  // QKV projection + fused RMSNorm/RoPE epilogue. grid 1D: 24 n-tiles x 64 m.
  gemm_bt<0><<<24 * 64, 256, 0, stream>>>(
      hs_b, qkvw_b, nullptr, q_raw, k_raw, v_buf, cosb, sinb, nqw, nkw,
      24, 64, 3 * Cn, Cn);

  flash_attn<<<Nn / 128 * Bn * Hn, 256, 0, stream>>>(q_raw, k_raw, v_buf, attn);

  // out projection. grid 1D: 8 n-tiles x 64 m.
  gemm_bt<1><<<8 * 64, 256, 0, stream>>>(
      attn, outw_b, out, nullptr, nullptr, nullptr, nullptr, nullptr, nullptr, nullptr,
      8, 64, Cn, Cn);
}